// Round 10
// baseline (85.321 us; speedup 1.0000x reference)
//
#include <hip/hip_runtime.h>

#define B_SZ 2048
#define IN_DIM 512
#define CTRL 512
#define N_LOC 65536
#define NSPLIT 128
#define EPSV 1e-8f
#define LOG2E 1.4426950408889634f

typedef __attribute__((ext_vector_type(8))) short bf16x8;
typedef __attribute__((ext_vector_type(4))) float f32x4;
typedef __attribute__((ext_vector_type(16))) float f32x16;
typedef __attribute__((ext_vector_type(4))) unsigned int u32x4;
typedef __attribute__((ext_vector_type(8))) unsigned short u16x8;

static __device__ __forceinline__ unsigned int cvtpk(float lo, float hi) {
  unsigned int r;
  asm("v_cvt_pk_bf16_f32 %0, %1, %2" : "=v"(r) : "v"(lo), "v"(hi));
  return r;
}
static __device__ __forceinline__ unsigned short f2bf_hw(float f) {
  return (unsigned short)(cvtpk(f, f) & 0xffffu);
}
static __device__ __forceinline__ float bf2f(unsigned short u) {
  return __builtin_bit_cast(float, ((unsigned int)u) << 16);
}
static __device__ __forceinline__ float exp2_fast(float x) {
  float r;
  asm("v_exp_f32 %0, %1" : "=v"(r) : "v"(x));
  return r;
}
static __device__ __forceinline__ void gld_lds16(const unsigned short* g, unsigned short* l) {
  __builtin_amdgcn_global_load_lds(
      (const __attribute__((address_space(1))) void*)g,
      (__attribute__((address_space(3))) void*)l, 16, 0, 0);
}

// ---------------- Kernel 1: M-prep (pre-swizzled) + Wkt transpose + hgemm ----------------
// blocks 0..1023: M tiles -> Mn_t (normalized*LOG2E), Mt_t (transposed), both stored in
//   the XOR-swizzled order so global_load_lds linear DMA lands them correctly.
// blocks 1024..1031: Wkt = bf16(Wk^T).
// blocks 1032..1287: h = tanh(x @ Wh + bh), self-contained (inline conversion).
__global__ __launch_bounds__(256) void k_mega(const float* __restrict__ x,
                                              const float* __restrict__ Wh,
                                              const float* __restrict__ Wk,
                                              const float* __restrict__ M,
                                              const float* __restrict__ bh,
                                              unsigned short* __restrict__ Wkt,
                                              unsigned short* __restrict__ Mn_t,
                                              unsigned short* __restrict__ Mt_t,
                                              float* __restrict__ h) {
  const int bx = blockIdx.x, t = threadIdx.x;
  if (bx < 1024) {
    const int b = bx;
    const int c4 = t & 15, lg = t >> 4;
    float vv[4][4], ss[4];
#pragma unroll
    for (int r = 0; r < 4; r++) {
      const int loc = b * 64 + lg * 4 + r;
      const float4 f = *(const float4*)&M[(size_t)loc * 64 + c4 * 4];
      vv[r][0] = f.x; vv[r][1] = f.y; vv[r][2] = f.z; vv[r][3] = f.w;
      ss[r] = f.x * f.x + f.y * f.y + f.z * f.z + f.w * f.w;
    }
#pragma unroll
    for (int r = 0; r < 4; r++)
#pragma unroll
      for (int off = 1; off < 16; off <<= 1) ss[r] += __shfl_xor(ss[r], off);
#pragma unroll
    for (int r = 0; r < 4; r++) {
      const int rr = lg * 4 + r;
      const float s = (1.f / (sqrtf(ss[r]) + EPSV)) * LOG2E;
      uint2 u;
      u.x = cvtpk(vv[r][0] * s, vv[r][1] * s);
      u.y = cvtpk(vv[r][2] * s, vv[r][3] * s);
      const int pos = b * 4096 + rr * 64 + (((c4 >> 1) ^ (rr & 7)) * 8) + (c4 & 1) * 4;
      *(uint2*)&Mn_t[pos] = u;
    }
#pragma unroll
    for (int j = 0; j < 4; j++) {
      const int rr = c4 * 4 + j;
      uint2 u;
      u.x = cvtpk(vv[0][j], vv[1][j]);
      u.y = cvtpk(vv[2][j], vv[3][j]);
      const int pos = b * 4096 + rr * 64 + (((lg >> 1) ^ (rr & 7)) * 8) + (lg & 1) * 4;
      *(uint2*)&Mt_t[pos] = u;
    }
  } else if (bx < 1032) {
    __shared__ float ld[64][65];
    const int ti = bx - 1024;  // k-block
#pragma unroll
    for (int i = 0; i < 4; i++) {
      const int c = t + i * 256;
      const int r = c >> 4, cc4 = (c & 15) * 4;
      const float4 v = *(const float4*)&Wk[(size_t)(ti * 64 + r) * 64 + cc4];
      ld[r][cc4] = v.x; ld[r][cc4 + 1] = v.y; ld[r][cc4 + 2] = v.z; ld[r][cc4 + 3] = v.w;
    }
    __syncthreads();
#pragma unroll
    for (int i = 0; i < 2; i++) {
      const int c = t + i * 256;
      const int col = c >> 3, k8 = (c & 7) * 8;
      u16x8 o;
#pragma unroll
      for (int j = 0; j < 4; j++) {
        unsigned int u = cvtpk(ld[k8 + 2 * j][col], ld[k8 + 2 * j + 1][col]);
        o[2 * j] = (unsigned short)u;
        o[2 * j + 1] = (unsigned short)(u >> 16);
      }
      *(u16x8*)&Wkt[(size_t)col * IN_DIM + ti * 64 + k8] = o;
    }
  } else {
    __shared__ __align__(16) unsigned short xs[64 * 40];
    __shared__ __align__(16) unsigned short whs[64 * 40];
    const int id2 = bx - 1032;
    const int bm = (id2 & 31) * 64, bn = (id2 >> 5) * 64;
    const int lane = t & 63, wv = t >> 6, lo = lane & 15, g = lane >> 4;
    f32x4 acc[4];
#pragma unroll
    for (int ct = 0; ct < 4; ct++) acc[ct] = (f32x4){0.f, 0.f, 0.f, 0.f};
    for (int k0 = 0; k0 < IN_DIM; k0 += 32) {
#pragma unroll
      for (int i = 0; i < 2; i++) {
        const int lin = t + i * 256;
        const int r = lin >> 3, q = lin & 7;
        const float4 v = *(const float4*)&x[(size_t)(bm + r) * IN_DIM + k0 + q * 4];
        uint2 u;
        u.x = cvtpk(v.x, v.y);
        u.y = cvtpk(v.z, v.w);
        *(uint2*)&xs[r * 40 + q * 4] = u;
      }
#pragma unroll
      for (int i = 0; i < 2; i++) {
        const int lin = t + i * 256;
        const int kk = lin >> 4, q = lin & 15;
        const float4 v = *(const float4*)&Wh[(size_t)(k0 + kk) * CTRL + bn + q * 4];
        const unsigned int a = cvtpk(v.x, v.y), b2 = cvtpk(v.z, v.w);
        whs[(q * 4 + 0) * 40 + kk] = (unsigned short)a;
        whs[(q * 4 + 1) * 40 + kk] = (unsigned short)(a >> 16);
        whs[(q * 4 + 2) * 40 + kk] = (unsigned short)b2;
        whs[(q * 4 + 3) * 40 + kk] = (unsigned short)(b2 >> 16);
      }
      __syncthreads();
      const bf16x8 afr = *(const bf16x8*)&xs[(16 * wv + lo) * 40 + 8 * g];
#pragma unroll
      for (int ct = 0; ct < 4; ct++) {
        const bf16x8 bfr = *(const bf16x8*)&whs[(16 * ct + lo) * 40 + 8 * g];
        acc[ct] = __builtin_amdgcn_mfma_f32_16x16x32_bf16(afr, bfr, acc[ct], 0, 0, 0);
      }
      __syncthreads();
    }
#pragma unroll
    for (int ct = 0; ct < 4; ct++)
#pragma unroll
      for (int q = 0; q < 4; q++) {
        const int row = bm + 16 * wv + 4 * g + q;
        const int col = bn + 16 * ct + lo;
        h[(size_t)row * CTRL + col] = tanhf(acc[ct][q] + bh[col]);
      }
  }
}

// ---------------- Kernel 2: read-key, 64 blocks x 32 rows + tail block ----------------
__global__ __launch_bounds__(256) void k_readkey(const float* __restrict__ h_,
                                                 const unsigned short* __restrict__ Wkt,
                                                 const float* __restrict__ bk,
                                                 const float* __restrict__ x,
                                                 const float* __restrict__ Wg,
                                                 const float* __restrict__ bg,
                                                 unsigned short* __restrict__ kn_bf,
                                                 float* __restrict__ out) {
  __shared__ float sAcc[4][32][65];
  __shared__ float red[4];
  const int t = threadIdx.x, lane = t & 63, w = t >> 6;
  const int l31 = lane & 31, hh = lane >> 5;
  if (blockIdx.x < 64) {
    const int row0 = blockIdx.x * 32;
    f32x16 acc[2];
    acc[0] = (f32x16)(0.f); acc[1] = (f32x16)(0.f);
#pragma unroll
    for (int kk = 0; kk < 8; kk++) {
      const int kb = 128 * w + 16 * kk + 8 * hh;
      const float4 a0 = *(const float4*)&h_[(size_t)(row0 + l31) * CTRL + kb];
      const float4 a1 = *(const float4*)&h_[(size_t)(row0 + l31) * CTRL + kb + 4];
      const u32x4 av = {cvtpk(a0.x, a0.y), cvtpk(a0.z, a0.w), cvtpk(a1.x, a1.y), cvtpk(a1.z, a1.w)};
      const bf16x8 afr = __builtin_bit_cast(bf16x8, av);
#pragma unroll
      for (int ct = 0; ct < 2; ct++) {
        const bf16x8 bfr = *(const bf16x8*)&Wkt[(size_t)(32 * ct + l31) * IN_DIM + kb];
        acc[ct] = __builtin_amdgcn_mfma_f32_32x32x16_bf16(afr, bfr, acc[ct], 0, 0, 0);
      }
    }
#pragma unroll
    for (int ct = 0; ct < 2; ct++)
#pragma unroll
      for (int r = 0; r < 16; r++)
        sAcc[w][(r & 3) + 8 * (r >> 2) + 4 * hh][32 * ct + l31] = acc[ct][r];
    __syncthreads();
    const int row = t >> 3, c8 = (t & 7) * 8;
    float v[8];
    float ss = 0.f;
#pragma unroll
    for (int j = 0; j < 8; j++) {
      const float s = sAcc[0][row][c8 + j] + sAcc[1][row][c8 + j] +
                      sAcc[2][row][c8 + j] + sAcc[3][row][c8 + j] + bk[c8 + j];
      v[j] = tanhf(s);
      ss += v[j] * v[j];
    }
    ss += __shfl_xor(ss, 1);
    ss += __shfl_xor(ss, 2);
    ss += __shfl_xor(ss, 4);
    const float inv = 1.f / (sqrtf(ss) + EPSV);
    u16x8 o;
#pragma unroll
    for (int j = 0; j < 4; j++) {
      const unsigned int u = cvtpk(v[2 * j] * inv, v[2 * j + 1] * inv);
      o[2 * j] = (unsigned short)u;
      o[2 * j + 1] = (unsigned short)(u >> 16);
    }
    *(u16x8*)&kn_bf[(size_t)(row0 + row) * 64 + c8] = o;
  } else {
    out[2048 + t] = h_[(size_t)(B_SZ - 1) * CTRL + t];
    out[2048 + 256 + t] = h_[(size_t)(B_SZ - 1) * CTRL + 256 + t];
    float p = x[(size_t)(B_SZ - 1) * IN_DIM + t] * Wg[t] +
              x[(size_t)(B_SZ - 1) * IN_DIM + 256 + t] * Wg[256 + t];
#pragma unroll
    for (int off = 32; off >= 1; off >>= 1) p += __shfl_xor(p, off);
    if ((t & 63) == 0) red[t >> 6] = p;
    __syncthreads();
    if (t == 0) out[2048 + 512] = red[0] + red[1] + red[2] + red[3] + bg[0];
  }
}

// ---------------- Kernel 3: fused attention partials ----------------
// grid (NSPLIT=128, 8): sp -> XCD = sp&7. 256 thr = 4 waves, 64 rows/wave.
// Staging via global_load_lds DMA (pre-swizzled source, linear LDS dest),
// inline cvtpk+permlane in PV (no held pkq), per-iter vmcnt(0)+barrier.
__global__ __launch_bounds__(256, 2) void k_attn(const unsigned short* __restrict__ kn_bf,
                                                 const unsigned short* __restrict__ Mn_t,
                                                 const unsigned short* __restrict__ Mt_t,
                                                 float* __restrict__ l_part,
                                                 unsigned short* __restrict__ r_bf,
                                                 float* __restrict__ wdump) {
  __shared__ __align__(16) unsigned short sMn[2][4096];
  __shared__ __align__(16) unsigned short sMt[2][4096];
  const int sp = blockIdx.x, rb = blockIdx.y;
  const int t = threadIdx.x, lane = t & 63, w = t >> 6;
  const int l31 = lane & 31, hh = lane >> 5, l7 = lane & 7;
  const int row0 = rb * 256 + 64 * w;

  // persistent kn B-frags for both rowsets
  bf16x8 bq[2][4];
#pragma unroll
  for (int rs = 0; rs < 2; rs++)
#pragma unroll
    for (int kk = 0; kk < 4; kk++)
      bq[rs][kk] =
          *(const bf16x8*)&kn_bf[(size_t)(row0 + 32 * rs + l31) * 64 + 16 * kk + 8 * hh];

  const int so = w * 1024 + lane * 8;  // per-lane source ushort offset within tile
  const int lo0 = w * 1024;            // wave-uniform LDS ushort base
  {
    const size_t gb = (size_t)(sp * 8) * 4096;
#pragma unroll
    for (int cc = 0; cc < 2; cc++) {
      gld_lds16(&Mn_t[gb + so + cc * 512], &sMn[0][lo0 + cc * 512]);
      gld_lds16(&Mt_t[gb + so + cc * 512], &sMt[0][lo0 + cc * 512]);
    }
  }
  asm volatile("s_waitcnt vmcnt(0)" ::: "memory");
  __syncthreads();

  f32x16 Racc[2][2];
#pragma unroll
  for (int rs = 0; rs < 2; rs++)
#pragma unroll
    for (int dt = 0; dt < 2; dt++) Racc[rs][dt] = (f32x16)(0.f);
  float lr0a = 0.f, lr0b = 0.f, lr1a = 0.f, lr1b = 0.f;

  for (int it = 0; it < 8; ++it) {
    const int cur = it & 1, nxt = cur ^ 1;
    if (it < 7) {
      const size_t gn = (size_t)(sp * 8 + it + 1) * 4096;
#pragma unroll
      for (int cc = 0; cc < 2; cc++) {
        gld_lds16(&Mn_t[gn + so + cc * 512], &sMn[nxt][lo0 + cc * 512]);
        gld_lds16(&Mt_t[gn + so + cc * 512], &sMt[nxt][lo0 + cc * 512]);
      }
    }

    // ---- phase 1: S^T tiles for both rowsets (A shared) ----
    f32x16 cst[2][2];
#pragma unroll
    for (int rs = 0; rs < 2; rs++)
#pragma unroll
      for (int lt = 0; lt < 2; lt++) cst[rs][lt] = (f32x16)(0.f);
    __builtin_amdgcn_s_setprio(1);
#pragma unroll
    for (int kk = 0; kk < 4; kk++) {
      const int koff = ((2 * kk + hh) ^ l7) * 8;
      const bf16x8 a0 = *(const bf16x8*)&sMn[cur][l31 * 64 + koff];
      const bf16x8 a1 = *(const bf16x8*)&sMn[cur][(32 + l31) * 64 + koff];
      cst[0][0] = __builtin_amdgcn_mfma_f32_32x32x16_bf16(a0, bq[0][kk], cst[0][0], 0, 0, 0);
      cst[0][1] = __builtin_amdgcn_mfma_f32_32x32x16_bf16(a1, bq[0][kk], cst[0][1], 0, 0, 0);
      cst[1][0] = __builtin_amdgcn_mfma_f32_32x32x16_bf16(a0, bq[1][kk], cst[1][0], 0, 0, 0);
      cst[1][1] = __builtin_amdgcn_mfma_f32_32x32x16_bf16(a1, bq[1][kk], cst[1][1], 0, 0, 0);
    }
    __builtin_amdgcn_s_setprio(0);

    // ---- softmax: p = exp2(s), no max tracking (|s| <= ~1.5) ----
#pragma unroll
    for (int r = 0; r < 16; r++) {
      cst[0][0][r] = exp2_fast(cst[0][0][r]); lr0a += cst[0][0][r];
      cst[0][1][r] = exp2_fast(cst[0][1][r]); lr0b += cst[0][1][r];
      cst[1][0][r] = exp2_fast(cst[1][0][r]); lr1a += cst[1][0][r];
      cst[1][1][r] = exp2_fast(cst[1][1][r]); lr1b += cst[1][1][r];
    }

    if (rb == 7 && w == 3 && l31 == 31) {  // batch row 2047 (rs=1)
#pragma unroll
      for (int lt = 0; lt < 2; lt++)
#pragma unroll
        for (int rr = 0; rr < 4; rr++)
          *(float4*)&wdump[sp * 512 + it * 64 + 32 * lt + 8 * rr + 4 * hh] =
              make_float4(cst[1][lt][4 * rr], cst[1][lt][4 * rr + 1], cst[1][lt][4 * rr + 2],
                          cst[1][lt][4 * rr + 3]);
    }

    // ---- phase 2: R += P @ Mt; pack+swap inlined per kk (each pair used once) ----
    __builtin_amdgcn_s_setprio(1);
#pragma unroll
    for (int kk = 0; kk < 4; kk++) {
      const int lt = kk >> 1, e8 = (kk & 1) * 8;
      const int koff = ((2 * kk + hh) ^ l7) * 8;
      const bf16x8 b0f = *(const bf16x8*)&sMt[cur][l31 * 64 + koff];
      const bf16x8 b1f = *(const bf16x8*)&sMt[cur][(32 + l31) * 64 + koff];
#pragma unroll
      for (int rs = 0; rs < 2; rs++) {
        const unsigned int p0 = cvtpk(cst[rs][lt][e8 + 0], cst[rs][lt][e8 + 1]);
        const unsigned int p1 = cvtpk(cst[rs][lt][e8 + 2], cst[rs][lt][e8 + 3]);
        const unsigned int p2 = cvtpk(cst[rs][lt][e8 + 4], cst[rs][lt][e8 + 5]);
        const unsigned int p3 = cvtpk(cst[rs][lt][e8 + 6], cst[rs][lt][e8 + 7]);
        auto s0 = __builtin_amdgcn_permlane32_swap(p2, p0, false, false);
        auto s1 = __builtin_amdgcn_permlane32_swap(p3, p1, false, false);
        const u32x4 aw = {(unsigned int)s0[1], (unsigned int)s1[1], (unsigned int)s0[0],
                          (unsigned int)s1[0]};
        const bf16x8 afr = __builtin_bit_cast(bf16x8, aw);
        Racc[rs][0] = __builtin_amdgcn_mfma_f32_32x32x16_bf16(afr, b0f, Racc[rs][0], 0, 0, 0);
        Racc[rs][1] = __builtin_amdgcn_mfma_f32_32x32x16_bf16(afr, b1f, Racc[rs][1], 0, 0, 0);
      }
    }
    __builtin_amdgcn_s_setprio(0);

    asm volatile("s_waitcnt vmcnt(0)" ::: "memory");
    __syncthreads();
  }

  float lr0 = lr0a + lr0b, lr1 = lr1a + lr1b;
  lr0 += __shfl_xor(lr0, 32);
  lr1 += __shfl_xor(lr1, 32);
  if (hh == 0) {
    l_part[(size_t)(row0 + l31) * NSPLIT + sp] = lr0;
    l_part[(size_t)(row0 + 32 + l31) * NSPLIT + sp] = lr1;
  }

#pragma unroll
  for (int rs = 0; rs < 2; rs++)
#pragma unroll
    for (int dt = 0; dt < 2; dt++)
#pragma unroll
      for (int r = 0; r < 16; r++) {
        const int brow = (r & 3) + 8 * (r >> 2) + 4 * hh;
        r_bf[((size_t)(row0 + 32 * rs + brow) * NSPLIT + sp) * 64 + 32 * dt + l31] =
            f2bf_hw(Racc[rs][dt][r]);
      }
}

// ---------------- Kernel 4: combine + output dot / w_read divide ----------------
__global__ __launch_bounds__(256) void k_post(const float* __restrict__ l_part,
                                              const unsigned short* __restrict__ r_bf,
                                              const float* __restrict__ h,
                                              const float* __restrict__ Wout,
                                              const float* __restrict__ bout,
                                              const float* __restrict__ wdump,
                                              float* __restrict__ out) {
  const int lane = threadIdx.x & 63, w = threadIdx.x >> 6;
  const int bx = blockIdx.x;
  if (bx < 512) {
    const int row = bx * 4 + w;
    float l = l_part[(size_t)row * NSPLIT + lane] + l_part[(size_t)row * NSPLIT + 64 + lane];
#pragma unroll
    for (int off = 32; off >= 1; off >>= 1) l += __shfl_xor(l, off);
    float rd = 0.f;
    for (int sp2 = 0; sp2 < NSPLIT; sp2++)
      rd += bf2f(r_bf[((size_t)row * NSPLIT + sp2) * 64 + lane]);
    rd /= l;
    float acc = Wout[CTRL + lane] * rd;
    for (int k = lane; k < CTRL; k += 64) acc += h[(size_t)row * CTRL + k] * Wout[k];
#pragma unroll
    for (int off = 32; off >= 1; off >>= 1) acc += __shfl_xor(acc, off);
    if (lane == 0) out[row] = acc + bout[0];
  } else {
    float l = l_part[(size_t)(B_SZ - 1) * NSPLIT + lane] +
              l_part[(size_t)(B_SZ - 1) * NSPLIT + 64 + lane];
#pragma unroll
    for (int off = 32; off >= 1; off >>= 1) l += __shfl_xor(l, off);
    const float rl = 1.f / l;
    const int i = ((bx - 512) * 256 + threadIdx.x) * 4;
    const float4 v = *(const float4*)&wdump[i];
    *(float4*)&out[2048 + 512 + 1 + i] = make_float4(v.x * rl, v.y * rl, v.z * rl, v.w * rl);
  }
}

extern "C" void kernel_launch(void* const* d_in, const int* in_sizes, int n_in,
                              void* d_out, int out_size, void* d_ws, size_t ws_size,
                              hipStream_t stream) {
  const float* x = (const float*)d_in[0];
  const float* Wh = (const float*)d_in[1];
  const float* bh = (const float*)d_in[2];
  const float* Wg = (const float*)d_in[3];
  const float* bg = (const float*)d_in[4];
  const float* Wk = (const float*)d_in[5];
  const float* bk = (const float*)d_in[6];
  const float* M = (const float*)d_in[7];
  const float* Wout = (const float*)d_in[8];
  const float* bout = (const float*)d_in[9];
  float* out = (float*)d_out;

  float* ws = (float*)d_ws;
  float* h = ws;                                   // 1,048,576 f (4 MB)
  float* l_part = h + 1048576;                     // 262,144 f (1 MB)
  float* wdump = l_part + 262144;                  // 65,536 f (0.25 MB)
  unsigned short* r_bf = (unsigned short*)(wdump + 65536);  // 16,777,216 us (32 MB)
  unsigned short* kn_bf = r_bf + 16777216;         // 131,072 us
  unsigned short* Mn_t = kn_bf + 131072;           // 4,194,304 us (8 MB)
  unsigned short* Mt_t = Mn_t + 4194304;           // 4,194,304 us (8 MB)
  unsigned short* Wkt = Mt_t + 4194304;            // 32,768 us  (total ~53.6 MB)

  hipLaunchKernelGGL(k_mega, dim3(1288), dim3(256), 0, stream,
                     x, Wh, Wk, M, bh, Wkt, Mn_t, Mt_t, h);
  hipLaunchKernelGGL(k_readkey, dim3(65), dim3(256), 0, stream,
                     h, Wkt, bk, x, Wg, bg, kn_bf, out);
  hipLaunchKernelGGL(k_attn, dim3(NSPLIT, 8), dim3(256), 0, stream,
                     kn_bf, Mn_t, Mt_t, l_part, r_bf, wdump);
  hipLaunchKernelGGL(k_post, dim3(512 + 64), dim3(256), 0, stream,
                     l_part, r_bf, h, Wout, bout, wdump, out);
}

// Round 11
// 80.475 us; speedup vs baseline: 1.0602x; 1.0602x over previous
//
#include <hip/hip_runtime.h>

#define B_SZ 2048
#define IN_DIM 512
#define CTRL 512
#define N_LOC 65536
#define NSPLIT 64
#define LPS (N_LOC / NSPLIT)   // 1024 locs per split, 16 tiles of 64
#define EPSV 1e-8f
#define LOG2E 1.4426950408889634f

typedef __attribute__((ext_vector_type(8))) short bf16x8;
typedef __attribute__((ext_vector_type(4))) float f32x4;
typedef __attribute__((ext_vector_type(16))) float f32x16;
typedef __attribute__((ext_vector_type(4))) unsigned int u32x4;
typedef __attribute__((ext_vector_type(8))) unsigned short u16x8;

static __device__ __forceinline__ unsigned int cvtpk(float lo, float hi) {
  unsigned int r;
  asm("v_cvt_pk_bf16_f32 %0, %1, %2" : "=v"(r) : "v"(lo), "v"(hi));
  return r;
}
static __device__ __forceinline__ unsigned short f2bf_hw(float f) {
  return (unsigned short)(cvtpk(f, f) & 0xffffu);
}
static __device__ __forceinline__ float bf2f(unsigned short u) {
  return __builtin_bit_cast(float, ((unsigned int)u) << 16);
}
static __device__ __forceinline__ float exp2_fast(float x) {
  float r;
  asm("v_exp_f32 %0, %1" : "=v"(r) : "v"(x));
  return r;
}

// ---------------- Kernel 1: M-prep (linear) + Wkt transpose + hgemm ----------------
// blocks 0..1023: M tiles -> Mn_t [tile][loc][d] (*invn*LOG2E), Mt_t [tile][d][loc].
// blocks 1024..1031: Wkt = bf16(Wk^T) [col][k].
// blocks 1032..1287: h = tanh(x @ Wh + bh), inline fp32->bf16 conversion.
__global__ __launch_bounds__(256) void k_mega(const float* __restrict__ x,
                                              const float* __restrict__ Wh,
                                              const float* __restrict__ Wk,
                                              const float* __restrict__ M,
                                              const float* __restrict__ bh,
                                              unsigned short* __restrict__ Wkt,
                                              unsigned short* __restrict__ Mn_t,
                                              unsigned short* __restrict__ Mt_t,
                                              float* __restrict__ h) {
  const int bx = blockIdx.x, t = threadIdx.x;
  if (bx < 1024) {
    const int b = bx;
    const int c4 = t & 15, lg = t >> 4;
    float vv[4][4], ss[4];
#pragma unroll
    for (int r = 0; r < 4; r++) {
      const int loc = b * 64 + lg * 4 + r;
      const float4 f = *(const float4*)&M[(size_t)loc * 64 + c4 * 4];
      vv[r][0] = f.x; vv[r][1] = f.y; vv[r][2] = f.z; vv[r][3] = f.w;
      ss[r] = f.x * f.x + f.y * f.y + f.z * f.z + f.w * f.w;
    }
#pragma unroll
    for (int r = 0; r < 4; r++)
#pragma unroll
      for (int off = 1; off < 16; off <<= 1) ss[r] += __shfl_xor(ss[r], off);
#pragma unroll
    for (int r = 0; r < 4; r++) {
      const float s = (1.f / (sqrtf(ss[r]) + EPSV)) * LOG2E;
      uint2 u;
      u.x = cvtpk(vv[r][0] * s, vv[r][1] * s);
      u.y = cvtpk(vv[r][2] * s, vv[r][3] * s);
      *(uint2*)&Mn_t[(size_t)b * 4096 + (lg * 4 + r) * 64 + c4 * 4] = u;
    }
#pragma unroll
    for (int j = 0; j < 4; j++) {
      uint2 u;
      u.x = cvtpk(vv[0][j], vv[1][j]);
      u.y = cvtpk(vv[2][j], vv[3][j]);
      *(uint2*)&Mt_t[(size_t)b * 4096 + (c4 * 4 + j) * 64 + lg * 4] = u;
    }
  } else if (bx < 1032) {
    __shared__ float ld[64][65];
    const int ti = bx - 1024;  // k-block
#pragma unroll
    for (int i = 0; i < 4; i++) {
      const int c = t + i * 256;
      const int r = c >> 4, cc4 = (c & 15) * 4;
      const float4 v = *(const float4*)&Wk[(size_t)(ti * 64 + r) * 64 + cc4];
      ld[r][cc4] = v.x; ld[r][cc4 + 1] = v.y; ld[r][cc4 + 2] = v.z; ld[r][cc4 + 3] = v.w;
    }
    __syncthreads();
#pragma unroll
    for (int i = 0; i < 2; i++) {
      const int c = t + i * 256;
      const int col = c >> 3, k8 = (c & 7) * 8;
      u16x8 o;
#pragma unroll
      for (int j = 0; j < 4; j++) {
        unsigned int u = cvtpk(ld[k8 + 2 * j][col], ld[k8 + 2 * j + 1][col]);
        o[2 * j] = (unsigned short)u;
        o[2 * j + 1] = (unsigned short)(u >> 16);
      }
      *(u16x8*)&Wkt[(size_t)col * IN_DIM + ti * 64 + k8] = o;
    }
  } else {
    __shared__ __align__(16) unsigned short xs[64 * 40];
    __shared__ __align__(16) unsigned short whs[64 * 40];
    const int id2 = bx - 1032;
    const int bm = (id2 & 31) * 64, bn = (id2 >> 5) * 64;
    const int lane = t & 63, wv = t >> 6, lo = lane & 15, g = lane >> 4;
    f32x4 acc[4];
#pragma unroll
    for (int ct = 0; ct < 4; ct++) acc[ct] = (f32x4){0.f, 0.f, 0.f, 0.f};
    for (int k0 = 0; k0 < IN_DIM; k0 += 32) {
#pragma unroll
      for (int i = 0; i < 2; i++) {
        const int lin = t + i * 256;
        const int r = lin >> 3, q = lin & 7;
        const float4 v = *(const float4*)&x[(size_t)(bm + r) * IN_DIM + k0 + q * 4];
        uint2 u;
        u.x = cvtpk(v.x, v.y);
        u.y = cvtpk(v.z, v.w);
        *(uint2*)&xs[r * 40 + q * 4] = u;
      }
#pragma unroll
      for (int i = 0; i < 2; i++) {
        const int lin = t + i * 256;
        const int kk = lin >> 4, q = lin & 15;
        const float4 v = *(const float4*)&Wh[(size_t)(k0 + kk) * CTRL + bn + q * 4];
        const unsigned int a = cvtpk(v.x, v.y), b2 = cvtpk(v.z, v.w);
        whs[(q * 4 + 0) * 40 + kk] = (unsigned short)a;
        whs[(q * 4 + 1) * 40 + kk] = (unsigned short)(a >> 16);
        whs[(q * 4 + 2) * 40 + kk] = (unsigned short)b2;
        whs[(q * 4 + 3) * 40 + kk] = (unsigned short)(b2 >> 16);
      }
      __syncthreads();
      const bf16x8 afr = *(const bf16x8*)&xs[(16 * wv + lo) * 40 + 8 * g];
#pragma unroll
      for (int ct = 0; ct < 4; ct++) {
        const bf16x8 bfr = *(const bf16x8*)&whs[(16 * ct + lo) * 40 + 8 * g];
        acc[ct] = __builtin_amdgcn_mfma_f32_16x16x32_bf16(afr, bfr, acc[ct], 0, 0, 0);
      }
      __syncthreads();
    }
#pragma unroll
    for (int ct = 0; ct < 4; ct++)
#pragma unroll
      for (int q = 0; q < 4; q++) {
        const int row = bm + 16 * wv + 4 * g + q;
        const int col = bn + 16 * ct + lo;
        h[(size_t)row * CTRL + col] = tanhf(acc[ct][q] + bh[col]);
      }
  }
}

// ---------------- Kernel 2: read-key, 64 blocks x 32 rows + tail block ----------------
__global__ __launch_bounds__(256) void k_readkey(const float* __restrict__ h_,
                                                 const unsigned short* __restrict__ Wkt,
                                                 const float* __restrict__ bk,
                                                 const float* __restrict__ x,
                                                 const float* __restrict__ Wg,
                                                 const float* __restrict__ bg,
                                                 unsigned short* __restrict__ kn_bf,
                                                 float* __restrict__ out) {
  __shared__ float sAcc[4][32][65];
  __shared__ float red[4];
  const int t = threadIdx.x, lane = t & 63, w = t >> 6;
  const int l31 = lane & 31, hh = lane >> 5;
  if (blockIdx.x < 64) {
    const int row0 = blockIdx.x * 32;
    f32x16 acc[2];
    acc[0] = (f32x16)(0.f); acc[1] = (f32x16)(0.f);
#pragma unroll
    for (int kk = 0; kk < 8; kk++) {
      const int kb = 128 * w + 16 * kk + 8 * hh;
      const float4 a0 = *(const float4*)&h_[(size_t)(row0 + l31) * CTRL + kb];
      const float4 a1 = *(const float4*)&h_[(size_t)(row0 + l31) * CTRL + kb + 4];
      const u32x4 av = {cvtpk(a0.x, a0.y), cvtpk(a0.z, a0.w), cvtpk(a1.x, a1.y), cvtpk(a1.z, a1.w)};
      const bf16x8 afr = __builtin_bit_cast(bf16x8, av);
#pragma unroll
      for (int ct = 0; ct < 2; ct++) {
        const bf16x8 bfr = *(const bf16x8*)&Wkt[(size_t)(32 * ct + l31) * IN_DIM + kb];
        acc[ct] = __builtin_amdgcn_mfma_f32_32x32x16_bf16(afr, bfr, acc[ct], 0, 0, 0);
      }
    }
#pragma unroll
    for (int ct = 0; ct < 2; ct++)
#pragma unroll
      for (int r = 0; r < 16; r++)
        sAcc[w][(r & 3) + 8 * (r >> 2) + 4 * hh][32 * ct + l31] = acc[ct][r];
    __syncthreads();
    const int row = t >> 3, c8 = (t & 7) * 8;
    float v[8];
    float ss = 0.f;
#pragma unroll
    for (int j = 0; j < 8; j++) {
      const float s = sAcc[0][row][c8 + j] + sAcc[1][row][c8 + j] +
                      sAcc[2][row][c8 + j] + sAcc[3][row][c8 + j] + bk[c8 + j];
      v[j] = tanhf(s);
      ss += v[j] * v[j];
    }
    ss += __shfl_xor(ss, 1);
    ss += __shfl_xor(ss, 2);
    ss += __shfl_xor(ss, 4);
    const float inv = 1.f / (sqrtf(ss) + EPSV);
    u16x8 o;
#pragma unroll
    for (int j = 0; j < 4; j++) {
      const unsigned int u = cvtpk(v[2 * j] * inv, v[2 * j + 1] * inv);
      o[2 * j] = (unsigned short)u;
      o[2 * j + 1] = (unsigned short)(u >> 16);
    }
    *(u16x8*)&kn_bf[(size_t)(row0 + row) * 64 + c8] = o;
  } else {
    out[2048 + t] = h_[(size_t)(B_SZ - 1) * CTRL + t];
    out[2048 + 256 + t] = h_[(size_t)(B_SZ - 1) * CTRL + 256 + t];
    float p = x[(size_t)(B_SZ - 1) * IN_DIM + t] * Wg[t] +
              x[(size_t)(B_SZ - 1) * IN_DIM + 256 + t] * Wg[256 + t];
#pragma unroll
    for (int off = 32; off >= 1; off >>= 1) p += __shfl_xor(p, off);
    if ((t & 63) == 0) red[t >> 6] = p;
    __syncthreads();
    if (t == 0) out[2048 + 512] = red[0] + red[1] + red[2] + red[3] + bg[0];
  }
}

// ---------------- Kernel 3: fused attention partials (R7-measured-best config) ----
// grid (NSPLIT=64, 8): sp -> XCD = sp&7. 256 thr = 4 waves, 64 rows/wave.
__global__ __launch_bounds__(256, 2) void k_attn(const unsigned short* __restrict__ kn_bf,
                                                 const unsigned short* __restrict__ Mn_t,
                                                 const unsigned short* __restrict__ Mt_t,
                                                 float* __restrict__ l_part,
                                                 unsigned short* __restrict__ r_bf,
                                                 float* __restrict__ wdump) {
  __shared__ __align__(16) unsigned short sMn[2][4096];
  __shared__ __align__(16) unsigned short sMt[2][4096];
  const int sp = blockIdx.x, rb = blockIdx.y;
  const int t = threadIdx.x, lane = t & 63, w = t >> 6;
  const int l31 = lane & 31, hh = lane >> 5, l7 = lane & 7;
  const int row0 = rb * 256 + 64 * w;

  // persistent kn B-frags for both rowsets
  bf16x8 bq[2][4];
#pragma unroll
  for (int rs = 0; rs < 2; rs++)
#pragma unroll
    for (int kk = 0; kk < 4; kk++)
      bq[rs][kk] =
          *(const bf16x8*)&kn_bf[(size_t)(row0 + 32 * rs + l31) * 64 + 16 * kk + 8 * hh];

  const int c0 = t, c1 = t + 256;
  const int r0 = c0 >> 3, d0 = r0 * 64 + (((c0 & 7) * 8) ^ ((r0 & 7) * 8));
  const int r1 = c1 >> 3, d1 = r1 * 64 + (((c1 & 7) * 8) ^ ((r1 & 7) * 8));
  {
    const size_t gb = (size_t)(sp * 16) * 4096;
    *(u16x8*)&sMn[0][d0] = *(const u16x8*)&Mn_t[gb + c0 * 8];
    *(u16x8*)&sMn[0][d1] = *(const u16x8*)&Mn_t[gb + c1 * 8];
    *(u16x8*)&sMt[0][d0] = *(const u16x8*)&Mt_t[gb + c0 * 8];
    *(u16x8*)&sMt[0][d1] = *(const u16x8*)&Mt_t[gb + c1 * 8];
  }
  __syncthreads();

  f32x16 Racc[2][2];
#pragma unroll
  for (int rs = 0; rs < 2; rs++)
#pragma unroll
    for (int dt = 0; dt < 2; dt++) Racc[rs][dt] = (f32x16)(0.f);
  float lr0a = 0.f, lr0b = 0.f, lr1a = 0.f, lr1b = 0.f;

  u16x8 rn0, rn1, rt0, rt1;
  for (int it = 0; it < 16; ++it) {
    const int cur = it & 1;
    if (it < 15) {
      const size_t gn = (size_t)(sp * 16 + it + 1) * 4096;
      rn0 = *(const u16x8*)&Mn_t[gn + c0 * 8];
      rn1 = *(const u16x8*)&Mn_t[gn + c1 * 8];
      rt0 = *(const u16x8*)&Mt_t[gn + c0 * 8];
      rt1 = *(const u16x8*)&Mt_t[gn + c1 * 8];
    }

    // ---- phase 1: S^T tiles for both rowsets (A shared) ----
    f32x16 cst[2][2];
#pragma unroll
    for (int rs = 0; rs < 2; rs++)
#pragma unroll
      for (int lt = 0; lt < 2; lt++) cst[rs][lt] = (f32x16)(0.f);
    __builtin_amdgcn_s_setprio(1);
#pragma unroll
    for (int kk = 0; kk < 4; kk++) {
      const int koff = ((2 * kk + hh) ^ l7) * 8;
      const bf16x8 a0 = *(const bf16x8*)&sMn[cur][l31 * 64 + koff];
      const bf16x8 a1 = *(const bf16x8*)&sMn[cur][(32 + l31) * 64 + koff];
      cst[0][0] = __builtin_amdgcn_mfma_f32_32x32x16_bf16(a0, bq[0][kk], cst[0][0], 0, 0, 0);
      cst[0][1] = __builtin_amdgcn_mfma_f32_32x32x16_bf16(a1, bq[0][kk], cst[0][1], 0, 0, 0);
      cst[1][0] = __builtin_amdgcn_mfma_f32_32x32x16_bf16(a0, bq[1][kk], cst[1][0], 0, 0, 0);
      cst[1][1] = __builtin_amdgcn_mfma_f32_32x32x16_bf16(a1, bq[1][kk], cst[1][1], 0, 0, 0);
    }
    __builtin_amdgcn_s_setprio(0);

    // ---- softmax: p = exp2(s), no max tracking (|s| <= ~1.5) ----
#pragma unroll
    for (int r = 0; r < 16; r++) {
      cst[0][0][r] = exp2_fast(cst[0][0][r]); lr0a += cst[0][0][r];
      cst[0][1][r] = exp2_fast(cst[0][1][r]); lr0b += cst[0][1][r];
      cst[1][0][r] = exp2_fast(cst[1][0][r]); lr1a += cst[1][0][r];
      cst[1][1][r] = exp2_fast(cst[1][1][r]); lr1b += cst[1][1][r];
    }

    if (rb == 7 && w == 3 && l31 == 31) {  // batch row 2047 lives in rs=1 here
#pragma unroll
      for (int lt = 0; lt < 2; lt++)
#pragma unroll
        for (int rr = 0; rr < 4; rr++)
          *(float4*)&wdump[sp * 1024 + it * 64 + 32 * lt + 8 * rr + 4 * hh] =
              make_float4(cst[1][lt][4 * rr], cst[1][lt][4 * rr + 1], cst[1][lt][4 * rr + 2],
                          cst[1][lt][4 * rr + 3]);
    }

    // pack all 8 bf16-pairs per (rs,lt)
    unsigned int pkq[2][2][8];
#pragma unroll
    for (int rs = 0; rs < 2; rs++)
#pragma unroll
      for (int lt = 0; lt < 2; lt++)
#pragma unroll
        for (int m = 0; m < 8; m++)
          pkq[rs][lt][m] = cvtpk(cst[rs][lt][2 * m], cst[rs][lt][2 * m + 1]);

    // ---- phase 2: R += P @ Mt; A-frags via permlane32_swap ----
#pragma unroll
    for (int kk = 0; kk < 4; kk++) {
      const int lt = kk >> 1, e4 = (kk & 1) * 4;
      const int koff = ((2 * kk + hh) ^ l7) * 8;
      const bf16x8 b0f = *(const bf16x8*)&sMt[cur][l31 * 64 + koff];
      const bf16x8 b1f = *(const bf16x8*)&sMt[cur][(32 + l31) * 64 + koff];
      __builtin_amdgcn_s_setprio(1);
#pragma unroll
      for (int rs = 0; rs < 2; rs++) {
        auto s0 = __builtin_amdgcn_permlane32_swap(pkq[rs][lt][e4 + 2], pkq[rs][lt][e4 + 0],
                                                   false, false);
        auto s1 = __builtin_amdgcn_permlane32_swap(pkq[rs][lt][e4 + 3], pkq[rs][lt][e4 + 1],
                                                   false, false);
        const u32x4 aw = {(unsigned int)s0[1], (unsigned int)s1[1], (unsigned int)s0[0],
                          (unsigned int)s1[0]};
        const bf16x8 afr = __builtin_bit_cast(bf16x8, aw);
        Racc[rs][0] = __builtin_amdgcn_mfma_f32_32x32x16_bf16(afr, b0f, Racc[rs][0], 0, 0, 0);
        Racc[rs][1] = __builtin_amdgcn_mfma_f32_32x32x16_bf16(afr, b1f, Racc[rs][1], 0, 0, 0);
      }
      __builtin_amdgcn_s_setprio(0);
    }

    if (it < 15) {
      const int nxt = cur ^ 1;
      *(u16x8*)&sMn[nxt][d0] = rn0; *(u16x8*)&sMn[nxt][d1] = rn1;
      *(u16x8*)&sMt[nxt][d0] = rt0; *(u16x8*)&sMt[nxt][d1] = rt1;
    }
    __syncthreads();
  }

  float lr0 = lr0a + lr0b, lr1 = lr1a + lr1b;
  lr0 += __shfl_xor(lr0, 32);
  lr1 += __shfl_xor(lr1, 32);
  if (hh == 0) {
    l_part[(size_t)(row0 + l31) * NSPLIT + sp] = lr0;
    l_part[(size_t)(row0 + 32 + l31) * NSPLIT + sp] = lr1;
  }

#pragma unroll
  for (int rs = 0; rs < 2; rs++)
#pragma unroll
    for (int dt = 0; dt < 2; dt++)
#pragma unroll
      for (int r = 0; r < 16; r++) {
        const int brow = (r & 3) + 8 * (r >> 2) + 4 * hh;
        r_bf[((size_t)(row0 + 32 * rs + brow) * NSPLIT + sp) * 64 + 32 * dt + l31] =
            f2bf_hw(Racc[rs][dt][r]);
      }
}

// ---------------- Kernel 4: combine + output dot / w_read divide ----------------
__global__ __launch_bounds__(256) void k_post(const float* __restrict__ l_part,
                                              const unsigned short* __restrict__ r_bf,
                                              const float* __restrict__ h,
                                              const float* __restrict__ Wout,
                                              const float* __restrict__ bout,
                                              const float* __restrict__ wdump,
                                              float* __restrict__ out) {
  const int lane = threadIdx.x & 63, w = threadIdx.x >> 6;
  const int bx = blockIdx.x;
  if (bx < 512) {
    const int row = bx * 4 + w;
    float l = l_part[(size_t)row * NSPLIT + lane];
#pragma unroll
    for (int off = 32; off >= 1; off >>= 1) l += __shfl_xor(l, off);
    float rd = 0.f;
    for (int sp2 = 0; sp2 < NSPLIT; sp2++)
      rd += bf2f(r_bf[((size_t)row * NSPLIT + sp2) * 64 + lane]);
    rd /= l;
    float acc = Wout[CTRL + lane] * rd;
    for (int k = lane; k < CTRL; k += 64) acc += h[(size_t)row * CTRL + k] * Wout[k];
#pragma unroll
    for (int off = 32; off >= 1; off >>= 1) acc += __shfl_xor(acc, off);
    if (lane == 0) out[row] = acc + bout[0];
  } else {
    float l = l_part[(size_t)(B_SZ - 1) * NSPLIT + lane];
#pragma unroll
    for (int off = 32; off >= 1; off >>= 1) l += __shfl_xor(l, off);
    const float rl = 1.f / l;
    const int i = ((bx - 512) * 256 + threadIdx.x) * 4;
    const float4 v = *(const float4*)&wdump[i];
    *(float4*)&out[2048 + 512 + 1 + i] = make_float4(v.x * rl, v.y * rl, v.z * rl, v.w * rl);
  }
}

extern "C" void kernel_launch(void* const* d_in, const int* in_sizes, int n_in,
                              void* d_out, int out_size, void* d_ws, size_t ws_size,
                              hipStream_t stream) {
  const float* x = (const float*)d_in[0];
  const float* Wh = (const float*)d_in[1];
  const float* bh = (const float*)d_in[2];
  const float* Wg = (const float*)d_in[3];
  const float* bg = (const float*)d_in[4];
  const float* Wk = (const float*)d_in[5];
  const float* bk = (const float*)d_in[6];
  const float* M = (const float*)d_in[7];
  const float* Wout = (const float*)d_in[8];
  const float* bout = (const float*)d_in[9];
  float* out = (float*)d_out;

  float* ws = (float*)d_ws;
  float* h = ws;                                   // 1,048,576 f (4 MB)
  float* l_part = h + 1048576;                     // 2048*64 = 131,072 f
  float* wdump = l_part + 131072;                  // 65,536 f
  unsigned short* r_bf = (unsigned short*)(wdump + 65536);  // 2048*64*64 us (16 MB)
  unsigned short* kn_bf = r_bf + 8388608;          // 131,072 us
  unsigned short* Mn_t = kn_bf + 131072;           // 4,194,304 us (8 MB)
  unsigned short* Mt_t = Mn_t + 4194304;           // 4,194,304 us (8 MB)
  unsigned short* Wkt = Mt_t + 4194304;            // 32,768 us  (total ~37.3 MB)

  hipLaunchKernelGGL(k_mega, dim3(1288), dim3(256), 0, stream,
                     x, Wh, Wk, M, bh, Wkt, Mn_t, Mt_t, h);
  hipLaunchKernelGGL(k_readkey, dim3(65), dim3(256), 0, stream,
                     h, Wkt, bk, x, Wg, bg, kn_bf, out);
  hipLaunchKernelGGL(k_attn, dim3(NSPLIT, 8), dim3(256), 0, stream,
                     kn_bf, Mn_t, Mt_t, l_part, r_bf, wdump);
  hipLaunchKernelGGL(k_post, dim3(512 + 64), dim3(256), 0, stream,
                     l_part, r_bf, h, Wout, bout, wdump, out);
}